// Round 1
// baseline (349.267 us; speedup 1.0000x reference)
//
#include <hip/hip_runtime.h>
#include <math.h>

// SkipGram negative-sampling loss on MI355X — round 6.
// Single change vs R5: wave-level software pipeline. All 48 indices are
// prefetched to SGPRs at entry; sample i+1's 24 row loads are issued
// (SGPR base + lane voffset) right after sample i's dots, BEFORE the
// butterfly reduce, and a sched_barrier(ALU-only-cross) keeps the VMEM
// there. Goal: ~24 loads (24KB) in flight per wave across the ~400-cycle
// reduce/transcendental phase every iteration.
// Discriminator: VGPR_Count must jump 40 -> ~110+. If it stays ~40-64 the
// compiler sank the prefetch and the experiment is void.

#define DIM   300
#define B_TOT 65536
#define K_NEG 10
#define NROW  (K_NEG + 2)   // u, pos_v, 10 negs

constexpr int BLOCKS = 4096;
constexpr int TPB    = 256;
constexpr int WAVES  = BLOCKS * (TPB / 64);   // 16384
constexpr int B_PER_WAVE = B_TOT / WAVES;     // 4

typedef float vf4 __attribute__((ext_vector_type(4)));

__device__ __forceinline__ float dot4(vf4 a, vf4 b) {
    vf4 p = a * b;
    return p.x + p.y + p.z + p.w;
}

__device__ __forceinline__ vf4 ld_nt(const vf4* p) {
    return __builtin_nontemporal_load(p);
}

// Row = 75 float4 (1200 B). Lane i covers chunk i; lanes 0..10 also cover
// chunks 64..74 (masked lanes re-read chunk `lane`; contribution zeroed —
// same line as the c0 load -> L1 hit, no extra fabric traffic).
__global__ __launch_bounds__(TPB, 4) void sg_main(
    const float* __restrict__ uw, const float* __restrict__ vw,
    const int* __restrict__ pos_u, const int* __restrict__ pos_v,
    const int* __restrict__ neg_v, float* __restrict__ block_sums)
{
    const int lane = threadIdx.x & 63;
    const int wib  = threadIdx.x >> 6;
    int gw = blockIdx.x * (TPB / 64) + wib;
    gw = __builtin_amdgcn_readfirstlane(gw);     // wave-uniform

    const bool c1ok = lane < (75 - 64);          // lanes 0..10
    const int  o2   = c1ok ? (64 + lane) : lane; // in-bounds fallback

    const int b0 = gw * B_PER_WAVE;

    // ---- Prefetch ALL indices for this wave's samples into SGPRs. ----
    // One latency hit at the top instead of a scalar-load stall per sample.
    int idx[B_PER_WAVE][NROW];
    #pragma unroll
    for (int i = 0; i < B_PER_WAVE; ++i) {
        idx[i][0] = __builtin_amdgcn_readfirstlane(pos_u[b0 + i]);
        idx[i][1] = __builtin_amdgcn_readfirstlane(pos_v[b0 + i]);
        #pragma unroll
        for (int k = 0; k < K_NEG; ++k)
            idx[i][2 + k] = __builtin_amdgcn_readfirstlane(neg_v[(b0 + i) * K_NEG + k]);
    }

    // Persistent payload registers: overwritten in place by each prefetch.
    vf4 c0[NROW];
    vf4 c1[NROW];

    // Issue all 24 row loads of sample i. Pair order (c0[j],c1[j]) so the
    // first consumer's vmcnt wait clears after ~4 returns, not all 24.
    // SGPR row base + shared lane voffset: no per-row 64-bit VGPR address.
    auto issue = [&](int i) {
        {
            const vf4* bu = (const vf4*)(uw + (size_t)idx[i][0] * DIM);
            c0[0] = ld_nt(bu + lane);            // u row: non-temporal
            c1[0] = ld_nt(bu + o2);
        }
        #pragma unroll
        for (int j = 1; j < NROW; ++j) {
            const vf4* bv = (const vf4*)(vw + (size_t)idx[i][j] * DIM);
            c0[j] = bv[lane];
            c1[j] = bv[o2];
        }
    };

    issue(0);                                    // prologue

    float acc = 0.f;

    #pragma unroll
    for (int i = 0; i < B_PER_WAVE; ++i) {
        const vf4 u0 = c0[0];
        const vf4 u1 = c1[0];

        float part[K_NEG + 1];
        #pragma unroll
        for (int j = 1; j < NROW; ++j) {
            float p = dot4(c0[j], u0);
            float q = dot4(c1[j], u1);
            part[j - 1] = p + (c1ok ? q : 0.f);
        }

        // ---- Software pipeline: next sample's loads fly over the reduce.
        if (i + 1 < B_PER_WAVE) issue(i + 1);
        // Only (S)ALU may cross: prefetch VMEM stays above the butterfly,
        // butterfly DS ops stay below.
        __builtin_amdgcn_sched_barrier(0x7);

        // Butterfly-reduce all 11 dots across the wave (result broadcast).
        #pragma unroll
        for (int s = 1; s < 64; s <<= 1) {
            #pragma unroll
            for (int j = 0; j < K_NEG + 1; ++j)
                part[j] += __shfl_xor(part[j], s, 64);
        }

        // pos: softplus(-score); neg: softplus(+score)
        float score = fminf(fmaxf(part[0], -10.f), 10.f);
        float loss = __logf(1.f + __expf(-score));
        #pragma unroll
        for (int k = 0; k < K_NEG; ++k) {
            float ns = fminf(fmaxf(part[k + 1], -10.f), 10.f);
            loss += __logf(1.f + __expf(ns));
        }
        acc += loss;   // uniform across lanes
    }

    __shared__ float red[TPB / 64];
    if (lane == 0) red[wib] = acc;
    __syncthreads();
    if (threadIdx.x == 0)
        block_sums[blockIdx.x] = red[0] + red[1] + red[2] + red[3];
}

__global__ __launch_bounds__(256) void sg_finalize(
    const float* __restrict__ bs, float* __restrict__ out)
{
    float s = 0.f;
    for (int i = threadIdx.x; i < BLOCKS; i += 256) s += bs[i];
    #pragma unroll
    for (int off = 1; off < 64; off <<= 1) s += __shfl_xor(s, off, 64);
    __shared__ float red[4];
    const int wave = threadIdx.x >> 6;
    if ((threadIdx.x & 63) == 0) red[wave] = s;
    __syncthreads();
    if (threadIdx.x == 0)
        out[0] = (red[0] + red[1] + red[2] + red[3]) * (1.0f / (float)B_TOT);
}

extern "C" void kernel_launch(void* const* d_in, const int* in_sizes, int n_in,
                              void* d_out, int out_size, void* d_ws, size_t ws_size,
                              hipStream_t stream) {
    const float* uw    = (const float*)d_in[0];
    const float* vw    = (const float*)d_in[1];
    const int*   pos_u = (const int*)d_in[2];
    const int*   pos_v = (const int*)d_in[3];
    const int*   neg_v = (const int*)d_in[4];
    float* out = (float*)d_out;
    float* block_sums = (float*)d_ws;

    sg_main<<<BLOCKS, TPB, 0, stream>>>(uw, vw, pos_u, pos_v, neg_v, block_sums);
    sg_finalize<<<1, 256, 0, stream>>>(block_sums, out);
}

// Round 2
// 344.518 us; speedup vs baseline: 1.0138x; 1.0138x over previous
//
#include <hip/hip_runtime.h>
#include <math.h>

// SkipGram negative-sampling loss on MI355X — round 7.
// R6 post-mortem: the software pipeline spilled (WRITE_SIZE 53MB, VGPR=64)
// because launch_bounds(256,4) only sets a MIN waves/EU — the compiler
// targeted 8 waves/EU (64 VGPRs) and scratch-spilled the 96-dword payload.
// Single change: pin waves/EU to exactly 4 via amdgpu_waves_per_eu(4,4) so
// regalloc plans for the 128-VGPR budget the pipeline needs. Also removed
// dead u0/u1 copies and interleaved load issue in (c0[j],c1[j]) pair order.
// Discriminator: VGPR_Count must be ~112-128 and WRITE_SIZE ~0.15MB.

#define DIM   300
#define B_TOT 65536
#define K_NEG 10
#define NROW  (K_NEG + 2)   // u, pos_v, 10 negs

constexpr int BLOCKS = 4096;
constexpr int TPB    = 256;
constexpr int WAVES  = BLOCKS * (TPB / 64);   // 16384
constexpr int B_PER_WAVE = B_TOT / WAVES;     // 4

typedef float vf4 __attribute__((ext_vector_type(4)));

__device__ __forceinline__ float dot4(vf4 a, vf4 b) {
    vf4 p = a * b;
    return p.x + p.y + p.z + p.w;
}

__device__ __forceinline__ vf4 ld_nt(const vf4* p) {
    return __builtin_nontemporal_load(p);
}

// Row = 75 float4 (1200 B). Lane i covers chunk i; lanes 0..10 also cover
// chunks 64..74 (masked lanes re-read chunk `lane`; contribution zeroed —
// same line as the c0 load -> L1 hit, no extra fabric traffic).
__global__
__attribute__((amdgpu_flat_work_group_size(256, 256)))
__attribute__((amdgpu_waves_per_eu(4, 4)))
void sg_main(
    const float* __restrict__ uw, const float* __restrict__ vw,
    const int* __restrict__ pos_u, const int* __restrict__ pos_v,
    const int* __restrict__ neg_v, float* __restrict__ block_sums)
{
    const int lane = threadIdx.x & 63;
    const int wib  = threadIdx.x >> 6;
    int gw = blockIdx.x * (TPB / 64) + wib;
    gw = __builtin_amdgcn_readfirstlane(gw);     // wave-uniform

    const bool c1ok = lane < (75 - 64);          // lanes 0..10
    const int  o2   = c1ok ? (64 + lane) : lane; // in-bounds fallback

    const int b0 = gw * B_PER_WAVE;

    // ---- All 48 indices for this wave's samples -> SGPRs (s_load). ----
    // Addresses are wave-uniform, so these compile to scalar loads; one
    // latency hit at the top instead of a stall per sample.
    int idx[B_PER_WAVE][NROW];
    #pragma unroll
    for (int i = 0; i < B_PER_WAVE; ++i) {
        idx[i][0] = __builtin_amdgcn_readfirstlane(pos_u[b0 + i]);
        idx[i][1] = __builtin_amdgcn_readfirstlane(pos_v[b0 + i]);
        #pragma unroll
        for (int k = 0; k < K_NEG; ++k)
            idx[i][2 + k] = __builtin_amdgcn_readfirstlane(neg_v[(b0 + i) * K_NEG + k]);
    }

    // Persistent payload registers: overwritten in place by each prefetch.
    vf4 c0[NROW];
    vf4 c1[NROW];

    // Issue all 24 row loads of sample i, interleaved (c0[j],c1[j]) so the
    // first consumer's vmcnt wait clears after 4 returns, not all 24.
    // SGPR row base + shared lane voffset: no per-row 64-bit VGPR address.
    auto issue = [&](int i) {
        {
            const vf4* bu = (const vf4*)(uw + (size_t)idx[i][0] * DIM);
            c0[0] = ld_nt(bu + lane);            // u row: non-temporal
            c1[0] = ld_nt(bu + o2);
        }
        #pragma unroll
        for (int j = 1; j < NROW; ++j) {
            const vf4* bv = (const vf4*)(vw + (size_t)idx[i][j] * DIM);
            c0[j] = bv[lane];
            c1[j] = bv[o2];
        }
    };

    issue(0);                                    // prologue

    float acc = 0.f;

    #pragma unroll
    for (int i = 0; i < B_PER_WAVE; ++i) {
        float part[K_NEG + 1];
        #pragma unroll
        for (int j = 1; j < NROW; ++j) {
            float p = dot4(c0[j], c0[0]);
            float q = dot4(c1[j], c1[0]);
            part[j - 1] = p + (c1ok ? q : 0.f);
        }

        // ---- Software pipeline: next sample's loads fly over the reduce.
        if (i + 1 < B_PER_WAVE) issue(i + 1);
        // Only (S)ALU may cross: prefetch VMEM stays above the butterfly,
        // butterfly DS ops stay below.
        __builtin_amdgcn_sched_barrier(0x7);

        // Butterfly-reduce all 11 dots across the wave (result broadcast).
        #pragma unroll
        for (int s = 1; s < 64; s <<= 1) {
            #pragma unroll
            for (int j = 0; j < K_NEG + 1; ++j)
                part[j] += __shfl_xor(part[j], s, 64);
        }

        // pos: softplus(-score); neg: softplus(+score)
        float score = fminf(fmaxf(part[0], -10.f), 10.f);
        float loss = __logf(1.f + __expf(-score));
        #pragma unroll
        for (int k = 0; k < K_NEG; ++k) {
            float ns = fminf(fmaxf(part[k + 1], -10.f), 10.f);
            loss += __logf(1.f + __expf(ns));
        }
        acc += loss;   // uniform across lanes
    }

    __shared__ float red[TPB / 64];
    if (lane == 0) red[wib] = acc;
    __syncthreads();
    if (threadIdx.x == 0)
        block_sums[blockIdx.x] = red[0] + red[1] + red[2] + red[3];
}

__global__ __launch_bounds__(256) void sg_finalize(
    const float* __restrict__ bs, float* __restrict__ out)
{
    float s = 0.f;
    for (int i = threadIdx.x; i < BLOCKS; i += 256) s += bs[i];
    #pragma unroll
    for (int off = 1; off < 64; off <<= 1) s += __shfl_xor(s, off, 64);
    __shared__ float red[4];
    const int wave = threadIdx.x >> 6;
    if ((threadIdx.x & 63) == 0) red[wave] = s;
    __syncthreads();
    if (threadIdx.x == 0)
        out[0] = (red[0] + red[1] + red[2] + red[3]) * (1.0f / (float)B_TOT);
}

extern "C" void kernel_launch(void* const* d_in, const int* in_sizes, int n_in,
                              void* d_out, int out_size, void* d_ws, size_t ws_size,
                              hipStream_t stream) {
    const float* uw    = (const float*)d_in[0];
    const float* vw    = (const float*)d_in[1];
    const int*   pos_u = (const int*)d_in[2];
    const int*   pos_v = (const int*)d_in[3];
    const int*   neg_v = (const int*)d_in[4];
    float* out = (float*)d_out;
    float* block_sums = (float*)d_ws;

    sg_main<<<BLOCKS, TPB, 0, stream>>>(uw, vw, pos_u, pos_v, neg_v, block_sums);
    sg_finalize<<<1, 256, 0, stream>>>(block_sums, out);
}